// Round 5
// baseline (1872.198 us; speedup 1.0000x reference)
//
#include <hip/hip_runtime.h>

#define NN 50000
#define NE 800000
#define LEAKY 0.2f

using bf16x8 = __attribute__((ext_vector_type(8))) short;
using f32x4  = __attribute__((ext_vector_type(4))) float;

static __device__ __forceinline__ unsigned short f2bf(float f) {
  unsigned u = __float_as_uint(f);
  u += 0x7FFF + ((u >> 16) & 1);  // round-to-nearest-even
  return (unsigned short)(u >> 16);
}
static __device__ __forceinline__ float bf2f(unsigned short h) {
  return __uint_as_float((unsigned)h << 16);
}

// ---------------------------------------------------------------- zero
__global__ void zero_ints(int* __restrict__ p, int n) {
  int i = blockIdx.x * blockDim.x + threadIdx.x;
  int s = gridDim.x * blockDim.x;
  for (; i < n; i += s) p[i] = 0;
}

// ---------------------------------------------------------------- degrees
__global__ void deg_kernel(const int* __restrict__ s1, const int* __restrict__ d1,
                           const int* __restrict__ s2, const int* __restrict__ d2,
                           int* od1, int* id1, int* od2, int* id2) {
  int i = blockIdx.x * blockDim.x + threadIdx.x;
  int st = gridDim.x * blockDim.x;
  for (int e = i; e < NE; e += st) {
    int a = s1[e], b = d1[e], c = s2[e], d = d2[e];
    atomicAdd(&od1[a], 1);
    atomicAdd(&id1[b], 1);
    atomicAdd(&od2[c], 1);
    atomicAdd(&id2[d], 1);
  }
}

__global__ void scale_kernel(const int* __restrict__ od1, const int* __restrict__ id1,
                             const int* __restrict__ od2, const int* __restrict__ id2,
                             float* io1, float* ii1, float* io2, float* ii2) {
  int i = blockIdx.x * blockDim.x + threadIdx.x;
  if (i < NN) {
    io1[i] = rsqrtf((float)(od1[i] > 0 ? od1[i] : 1));
    ii1[i] = rsqrtf((float)(id1[i] > 0 ? id1[i] : 1));
    io2[i] = rsqrtf((float)(od2[i] > 0 ? od2[i] : 1));
    ii2[i] = rsqrtf((float)(id2[i] > 0 ? id2[i] : 1));
  }
}

// ---------------------------------------------------------------- scan (row_ptr)
__global__ void scan_kernel(const int* __restrict__ id1, const int* __restrict__ id2,
                            int* rp1, int* rp2) {
  const int* deg = blockIdx.x ? id2 : id1;
  int* rp = blockIdx.x ? rp2 : rp1;
  __shared__ int sm[1024];
  __shared__ int carry;
  int t = threadIdx.x;
  if (t == 0) carry = 0;
  __syncthreads();
  for (int base = 0; base < NN; base += 1024) {
    int v = (base + t < NN) ? deg[base + t] : 0;
    sm[t] = v;
    __syncthreads();
    #pragma unroll
    for (int o = 1; o < 1024; o <<= 1) {
      int add = (t >= o) ? sm[t - o] : 0;
      __syncthreads();
      sm[t] += add;
      __syncthreads();
    }
    if (base + t < NN) rp[base + t] = carry + sm[t] - v;  // exclusive
    __syncthreads();
    if (t == 0) carry += sm[1023];
    __syncthreads();
  }
  if (t == 0) rp[NN] = carry;
}

// ---------------------------------------------------------------- CSR fill
__global__ void fill_kernel(const int* __restrict__ s1, const int* __restrict__ d1,
                            const int* __restrict__ s2, const int* __restrict__ d2,
                            const int* __restrict__ rp1, const int* __restrict__ rp2,
                            int* fill1, int* fill2, int* col1, int* col2) {
  int i = blockIdx.x * blockDim.x + threadIdx.x;
  int st = gridDim.x * blockDim.x;
  for (int e = i; e < NE; e += st) {
    int sa = s1[e], da = d1[e], sb = s2[e], db = d2[e];
    int pa = atomicAdd(&fill1[da], 1);
    int pb = atomicAdd(&fill2[db], 1);
    col1[rp1[da] + pa] = sa;
    col2[rp2[db] + pb] = sb;
  }
}

// ---------------------------------------------------------------- SpMM gather -> split bf16
// One wave per dst node: agg = inv_in[dst] * sum inv_out[src]*x[src,:],
// emitted as hi/lo bf16 planes of width KP (zero-padded k in [F,KP)).
template <int F, int KP>
__global__ __launch_bounds__(256) void spmm_kernel(
    const float* __restrict__ x, const int* __restrict__ rp, const int* __restrict__ col,
    const float* __restrict__ inv_out, const float* __restrict__ inv_in,
    short* __restrict__ hi, short* __restrict__ lo) {
  constexpr int F4 = F / 4;
  constexpr int P4 = KP / 4;
  constexpr int NI = (P4 + 63) / 64;
  int gw = (blockIdx.x * blockDim.x + threadIdx.x) >> 6;
  int lane = threadIdx.x & 63;
  int nw = (gridDim.x * blockDim.x) >> 6;
  const float4* __restrict__ x4 = (const float4*)x;
  for (int node = gw; node < NN; node += nw) {
    float4 acc[NI];
    #pragma unroll
    for (int i = 0; i < NI; ++i) acc[i] = make_float4(0.f, 0.f, 0.f, 0.f);
    int beg = rp[node], end = rp[node + 1];
    for (int j = beg; j < end; ++j) {
      int s = col[j];
      float w = inv_out[s];
      #pragma unroll
      for (int i = 0; i < NI; ++i) {
        int idx = i * 64 + lane;
        if (idx < F4) {
          float4 v = x4[(size_t)s * F4 + idx];
          acc[i].x += v.x * w;
          acc[i].y += v.y * w;
          acc[i].z += v.z * w;
          acc[i].w += v.w * w;
        }
      }
    }
    float wi = inv_in[node];
    #pragma unroll
    for (int i = 0; i < NI; ++i) {
      int idx = i * 64 + lane;
      if (idx < P4) {
        float4 v = acc[i];
        v.x *= wi; v.y *= wi; v.z *= wi; v.w *= wi;
        unsigned short hx = f2bf(v.x), hy = f2bf(v.y), hz = f2bf(v.z), hw = f2bf(v.w);
        short4 h = make_short4((short)hx, (short)hy, (short)hz, (short)hw);
        short4 l = make_short4((short)f2bf(v.x - bf2f(hx)), (short)f2bf(v.y - bf2f(hy)),
                               (short)f2bf(v.z - bf2f(hz)), (short)f2bf(v.w - bf2f(hw)));
        *(short4*)&hi[(size_t)node * KP + idx * 4] = h;
        *(short4*)&lo[(size_t)node * KP + idx * 4] = l;
      }
    }
  }
}

// ---------------------------------------------------------------- W pre-split
// W [K][Nc] fp32 -> Wh/Wl bf16 in LDS-image subtile-fragment order:
// chunk c2 = nb2*KB + kb covers cols [nb2*256, nb2*256+256), k [kb*32, kb*32+32).
// within chunk (8192 shorts): off = (nl>>4)*512 + ((kk>>3)*16 + (nl&15))*8 + (kk&7).
__global__ void wsplit(const float* __restrict__ W, short* __restrict__ Wh,
                       short* __restrict__ Wl, int K, int Nc, int KB) {
  int total = 2 * KB * 8192;
  int i = blockIdx.x * blockDim.x + threadIdx.x;
  int st = gridDim.x * blockDim.x;
  for (; i < total; i += st) {
    int c2 = i >> 13;
    int e = i & 8191;
    int kk = e >> 8;           // 0..31
    int rn = e & 255;          // 0..255 (fast -> coalesced W read)
    int nb2 = c2 / KB;
    int kb = c2 - nb2 * KB;
    int n = nb2 * 256 + rn;
    int k = kb * 32 + kk;
    float v = (n < Nc && k < K) ? W[(size_t)k * Nc + n] : 0.f;
    unsigned short h = f2bf(v);
    unsigned short l = f2bf(v - bf2f(h));
    size_t o = (size_t)c2 * 8192 + (rn >> 4) * 512 + ((kk >> 3) * 16 + (rn & 15)) * 8 + (kk & 7);
    Wh[o] = (short)h;
    Wl[o] = (short)l;
  }
}

// ---------------------------------------------------------------- MFMA GEMM (pre-split bf16)
// out[M,Nc] = epilogue(A1@W1 (+ A2@W2 if DUAL) + b1 (+ b2))
// EPI 0: leaky(v); EPI 1: leaky(v)+T (T==out in-place safe); EPI 2: v.
// Tile 128x256, BK=32, 4 waves (2x2 of 64x128). LDS in 16x32 subtile-fragment
// order -> all ds_read_b128/ds_write_b128 are base+lane*16 (conflict-free).
template <int EPI, int DUAL>
__global__ __launch_bounds__(256) void mgemm(
    const short* __restrict__ A1h, const short* __restrict__ A1l,
    const short* __restrict__ A2h, const short* __restrict__ A2l,
    const short* __restrict__ W1h, const short* __restrict__ W1l,
    const short* __restrict__ W2h, const short* __restrict__ W2l,
    const float* __restrict__ b1, const float* __restrict__ b2,
    const float* __restrict__ T, float* __restrict__ out,
    int M, int Nc, int KB, int KP) {
  __shared__ short Ah[4096], Al[4096];  // 128 rows x 32 k (8 subtiles)
  __shared__ short Bh[8192], Bl[8192];  // 256 cols x 32 k (16 subtiles)

  const int tid = threadIdx.x;
  const int nwg = gridDim.x;
  // bijective chunked XCD swizzle (m204): contiguous wgid per XCD
  const int q = nwg >> 3, r = nwg & 7;
  const int xcd = blockIdx.x & 7, loc = blockIdx.x >> 3;
  const int wgid = ((xcd < r) ? xcd * (q + 1) : r * (q + 1) + (xcd - r) * q) + loc;
  const int nb = wgid & 1;   // 2 col-blocks share one A panel (same XCD)
  const int m0 = (wgid >> 1) * 128;
  const int n0 = nb * 256;

  const int lane = tid & 63;
  const int wid = tid >> 6;
  const int wr = (wid >> 1) * 64;   // wave row offset: 0 / 64
  const int wc = (wid & 1) * 128;   // wave col offset: 0 / 128

  f32x4 acc[4][8];
  #pragma unroll
  for (int i = 0; i < 4; ++i)
    #pragma unroll
    for (int j = 0; j < 8; ++j) acc[i][j] = (f32x4)(0.f);

  for (int kb = 0; kb < KB; ++kb) {
    #pragma unroll
    for (int ch = 0; ch < 1 + DUAL; ++ch) {
      const short* __restrict__ Asrch = ch ? A2h : A1h;
      const short* __restrict__ Asrcl = ch ? A2l : A1l;
      const short* __restrict__ Wsrch = ch ? W2h : W1h;
      const short* __restrict__ Wsrcl = ch ? W2l : W1l;
      // ---- stage A: 512 granules(16B)/plane, granule g -> lds short-off g*8
      #pragma unroll
      for (int it = 0; it < 2; ++it) {
        int g = it * 256 + tid;
        int w = g & 63;
        int rrow = m0 + (g >> 6) * 16 + (w & 15);
        int ko = (w >> 4) * 8;
        uint4 vh = make_uint4(0u, 0u, 0u, 0u), vl = vh;
        if (rrow < M) {
          size_t ga = (size_t)rrow * KP + kb * 32 + ko;
          vh = *(const uint4*)(Asrch + ga);
          vl = *(const uint4*)(Asrcl + ga);
        }
        *(uint4*)&Ah[g * 8] = vh;
        *(uint4*)&Al[g * 8] = vl;
      }
      // ---- stage B: linear copy of pre-ordered chunk (1024 granules/plane)
      {
        size_t wb = ((size_t)(nb * KB + kb)) * 8192;
        #pragma unroll
        for (int it = 0; it < 4; ++it) {
          int g = it * 256 + tid;
          *(uint4*)&Bh[g * 8] = *(const uint4*)(Wsrch + wb + g * 8);
          *(uint4*)&Bl[g * 8] = *(const uint4*)(Wsrcl + wb + g * 8);
        }
      }
      __syncthreads();
      // ---- compute: frag reads are base + lane*16 (conflict-free)
      {
        bf16x8 fah[4], fal[4];
        #pragma unroll
        for (int i = 0; i < 4; ++i) {
          int sub = (wr >> 4) + i;
          fah[i] = *(const bf16x8*)&Ah[sub * 512 + lane * 8];
          fal[i] = *(const bf16x8*)&Al[sub * 512 + lane * 8];
        }
        #pragma unroll
        for (int j = 0; j < 8; ++j) {
          int sub = (wc >> 4) + j;
          bf16x8 fbh = *(const bf16x8*)&Bh[sub * 512 + lane * 8];
          bf16x8 fbl = *(const bf16x8*)&Bl[sub * 512 + lane * 8];
          #pragma unroll
          for (int i = 0; i < 4; ++i) {
            acc[i][j] = __builtin_amdgcn_mfma_f32_16x16x32_bf16(fah[i], fbh, acc[i][j], 0, 0, 0);
            acc[i][j] = __builtin_amdgcn_mfma_f32_16x16x32_bf16(fah[i], fbl, acc[i][j], 0, 0, 0);
            acc[i][j] = __builtin_amdgcn_mfma_f32_16x16x32_bf16(fal[i], fbh, acc[i][j], 0, 0, 0);
          }
        }
      }
      __syncthreads();
    }
  }

  // ---- epilogue: C/D layout col = lane&15, row = (lane>>4)*4 + reg
  #pragma unroll
  for (int i = 0; i < 4; ++i) {
    #pragma unroll
    for (int rr = 0; rr < 4; ++rr) {
      int rg = m0 + wr + i * 16 + (lane >> 4) * 4 + rr;
      if (rg >= M) continue;
      #pragma unroll
      for (int j = 0; j < 8; ++j) {
        int c = n0 + wc + j * 16 + (lane & 15);
        if (c >= Nc) continue;
        float v = acc[i][j][rr] + b1[c];
        if (DUAL) v += b2[c];
        if (EPI == 0 || EPI == 1) v = v > 0.f ? v : LEAKY * v;
        if (EPI == 1) v += T[(size_t)rg * Nc + c];
        out[(size_t)rg * Nc + c] = v;
      }
    }
  }
}

// ---------------------------------------------------------------- launch
extern "C" void kernel_launch(void* const* d_in, const int* in_sizes, int n_in,
                              void* d_out, int out_size, void* d_ws, size_t ws_size,
                              hipStream_t stream) {
  const float* emb = (const float*)d_in[0];
  const float* Wa1 = (const float*)d_in[1];
  const float* ba1 = (const float*)d_in[2];
  const float* Wa2 = (const float*)d_in[3];
  const float* ba2 = (const float*)d_in[4];
  const float* Wb1 = (const float*)d_in[5];
  const float* bb1 = (const float*)d_in[6];
  const float* Wb2 = (const float*)d_in[7];
  const float* bb2 = (const float*)d_in[8];
  const int* src1 = (const int*)d_in[9];
  const int* dst1 = (const int*)d_in[10];
  const int* src2 = (const int*)d_in[11];
  const int* dst2 = (const int*)d_in[12];
  float* out = (float*)d_out;

  char* ws = (char*)d_ws;
  size_t off = 0;
  auto alloc = [&](size_t nbytes) -> void* {
    off = (off + 255) & ~(size_t)255;
    void* p = ws + off;
    off += nbytes;
    return p;
  };
  int* od1 = (int*)alloc(NN * 4);
  int* id1 = (int*)alloc(NN * 4);
  int* od2 = (int*)alloc(NN * 4);
  int* id2 = (int*)alloc(NN * 4);
  int* fill1 = (int*)alloc(NN * 4);
  int* fill2 = (int*)alloc(NN * 4);
  int* rp1 = (int*)alloc((NN + 1) * 4);
  int* rp2 = (int*)alloc((NN + 1) * 4);
  int* col1 = (int*)alloc((size_t)NE * 4);
  int* col2 = (int*)alloc((size_t)NE * 4);
  float* io1 = (float*)alloc(NN * 4);
  float* ii1 = (float*)alloc(NN * 4);
  float* io2 = (float*)alloc(NN * 4);
  float* ii2 = (float*)alloc(NN * 4);
  const int KB1 = 10;  // k-tiles for K=300 (pad 320)
  const int KB2 = 13;  // k-tiles for K=400 (pad 416)
  short* Wa1h = (short*)alloc((size_t)2 * KB1 * 8192 * 2);
  short* Wa1l = (short*)alloc((size_t)2 * KB1 * 8192 * 2);
  short* Wb1h = (short*)alloc((size_t)2 * KB1 * 8192 * 2);
  short* Wb1l = (short*)alloc((size_t)2 * KB1 * 8192 * 2);
  short* Wa2h = (short*)alloc((size_t)2 * KB2 * 8192 * 2);
  short* Wa2l = (short*)alloc((size_t)2 * KB2 * 8192 * 2);
  short* Wb2h = (short*)alloc((size_t)2 * KB2 * 8192 * 2);
  short* Wb2l = (short*)alloc((size_t)2 * KB2 * 8192 * 2);
  short* A1h = (short*)alloc((size_t)NN * 416 * 2);  // hi plane (hop1: stride 320)
  short* A1l = (short*)alloc((size_t)NN * 416 * 2);
  short* A2h = (short*)alloc((size_t)NN * 416 * 2);
  short* A2l = (short*)alloc((size_t)NN * 416 * 2);
  float* X = (float*)d_out;  // hop-1 intermediate [NN x 400] lives in d_out

  int nz = (int)(((char*)fill2 - (char*)od1) / 4) + NN;
  zero_ints<<<256, 256, 0, stream>>>(od1, nz);

  deg_kernel<<<1024, 256, 0, stream>>>(src1, dst1, src2, dst2, od1, id1, od2, id2);
  scale_kernel<<<(NN + 255) / 256, 256, 0, stream>>>(od1, id1, od2, id2, io1, ii1, io2, ii2);
  scan_kernel<<<2, 1024, 0, stream>>>(id1, id2, rp1, rp2);
  fill_kernel<<<1024, 256, 0, stream>>>(src1, dst1, src2, dst2, rp1, rp2,
                                        fill1, fill2, col1, col2);

  wsplit<<<320, 256, 0, stream>>>(Wa1, Wa1h, Wa1l, 300, 400, KB1);
  wsplit<<<320, 256, 0, stream>>>(Wb1, Wb1h, Wb1l, 300, 400, KB1);
  wsplit<<<416, 256, 0, stream>>>(Wa2, Wa2h, Wa2l, 400, 512, KB2);
  wsplit<<<416, 256, 0, stream>>>(Wb2, Wb2h, Wb2l, 400, 512, KB2);

  const int NWG = 2 * ((NN + 127) / 128);  // 782

  // hop 1: x = leaky(gcn1) + leaky(gcn2), parked in d_out[:, :400]
  spmm_kernel<300, 320><<<12500, 256, 0, stream>>>(emb, rp1, col1, io1, ii1, A1h, A1l);
  mgemm<0, 0><<<NWG, 256, 0, stream>>>(A1h, A1l, nullptr, nullptr, Wa1h, Wa1l,
                                       nullptr, nullptr, ba1, nullptr, nullptr, X,
                                       NN, 400, KB1, 320);
  spmm_kernel<300, 320><<<12500, 256, 0, stream>>>(emb, rp2, col2, io2, ii2, A1h, A1l);
  mgemm<1, 0><<<NWG, 256, 0, stream>>>(A1h, A1l, nullptr, nullptr, Wb1h, Wb1l,
                                       nullptr, nullptr, bb1, nullptr, X, X,
                                       NN, 400, KB1, 320);

  // hop 2: y = agg1@Wa2 + agg2@Wb2 + ba2 + bb2 (fused dual-chain GEMM)
  spmm_kernel<400, 416><<<12500, 256, 0, stream>>>(X, rp1, col1, io1, ii1, A1h, A1l);
  spmm_kernel<400, 416><<<12500, 256, 0, stream>>>(X, rp2, col2, io2, ii2, A2h, A2l);
  mgemm<2, 1><<<NWG, 256, 0, stream>>>(A1h, A1l, A2h, A2l, Wa2h, Wa2l, Wb2h, Wb2l,
                                       ba2, bb2, nullptr, out, NN, 512, KB2, 416);
}

// Round 6
// 1602.660 us; speedup vs baseline: 1.1682x; 1.1682x over previous
//
#include <hip/hip_runtime.h>

#define NN 50000
#define NE 800000
#define LEAKY 0.2f

using bf16x8 = __attribute__((ext_vector_type(8))) short;
using f32x4  = __attribute__((ext_vector_type(4))) float;

static __device__ __forceinline__ unsigned short f2bf(float f) {
  unsigned u = __float_as_uint(f);
  u += 0x7FFF + ((u >> 16) & 1);  // round-to-nearest-even
  return (unsigned short)(u >> 16);
}
static __device__ __forceinline__ float bf2f(unsigned short h) {
  return __uint_as_float((unsigned)h << 16);
}

// async global->LDS, 16B per lane; LDS dest = uniform base + lane*16
static __device__ __forceinline__ void gload16(const short* g, short* l) {
  __builtin_amdgcn_global_load_lds(
      (const __attribute__((address_space(1))) void*)g,
      (__attribute__((address_space(3))) void*)l, 16, 0, 0);
}

// ---------------------------------------------------------------- zero
__global__ void zero_ints(int* __restrict__ p, int n) {
  int i = blockIdx.x * blockDim.x + threadIdx.x;
  int s = gridDim.x * blockDim.x;
  for (; i < n; i += s) p[i] = 0;
}

// ---------------------------------------------------------------- degrees
__global__ void deg_kernel(const int* __restrict__ s1, const int* __restrict__ d1,
                           const int* __restrict__ s2, const int* __restrict__ d2,
                           int* od1, int* id1, int* od2, int* id2) {
  int i = blockIdx.x * blockDim.x + threadIdx.x;
  int st = gridDim.x * blockDim.x;
  for (int e = i; e < NE; e += st) {
    int a = s1[e], b = d1[e], c = s2[e], d = d2[e];
    atomicAdd(&od1[a], 1);
    atomicAdd(&id1[b], 1);
    atomicAdd(&od2[c], 1);
    atomicAdd(&id2[d], 1);
  }
}

__global__ void scale_kernel(const int* __restrict__ od1, const int* __restrict__ id1,
                             const int* __restrict__ od2, const int* __restrict__ id2,
                             float* io1, float* ii1, float* io2, float* ii2) {
  int i = blockIdx.x * blockDim.x + threadIdx.x;
  if (i < NN) {
    io1[i] = rsqrtf((float)(od1[i] > 0 ? od1[i] : 1));
    ii1[i] = rsqrtf((float)(id1[i] > 0 ? id1[i] : 1));
    io2[i] = rsqrtf((float)(od2[i] > 0 ? od2[i] : 1));
    ii2[i] = rsqrtf((float)(id2[i] > 0 ? id2[i] : 1));
  }
}

// ---------------------------------------------------------------- scan (row_ptr)
__global__ void scan_kernel(const int* __restrict__ id1, const int* __restrict__ id2,
                            int* rp1, int* rp2) {
  const int* deg = blockIdx.x ? id2 : id1;
  int* rp = blockIdx.x ? rp2 : rp1;
  __shared__ int sm[1024];
  __shared__ int carry;
  int t = threadIdx.x;
  if (t == 0) carry = 0;
  __syncthreads();
  for (int base = 0; base < NN; base += 1024) {
    int v = (base + t < NN) ? deg[base + t] : 0;
    sm[t] = v;
    __syncthreads();
    #pragma unroll
    for (int o = 1; o < 1024; o <<= 1) {
      int add = (t >= o) ? sm[t - o] : 0;
      __syncthreads();
      sm[t] += add;
      __syncthreads();
    }
    if (base + t < NN) rp[base + t] = carry + sm[t] - v;  // exclusive
    __syncthreads();
    if (t == 0) carry += sm[1023];
    __syncthreads();
  }
  if (t == 0) rp[NN] = carry;
}

// ---------------------------------------------------------------- CSR fill
__global__ void fill_kernel(const int* __restrict__ s1, const int* __restrict__ d1,
                            const int* __restrict__ s2, const int* __restrict__ d2,
                            const int* __restrict__ rp1, const int* __restrict__ rp2,
                            int* fill1, int* fill2, int* col1, int* col2) {
  int i = blockIdx.x * blockDim.x + threadIdx.x;
  int st = gridDim.x * blockDim.x;
  for (int e = i; e < NE; e += st) {
    int sa = s1[e], da = d1[e], sb = s2[e], db = d2[e];
    int pa = atomicAdd(&fill1[da], 1);
    int pb = atomicAdd(&fill2[db], 1);
    col1[rp1[da] + pa] = sa;
    col2[rp2[db] + pb] = sb;
  }
}

// ---------------------------------------------------------------- SpMM gather -> split bf16
// One wave per dst node. Output planes in TILED-FRAGMENT order (same as W):
// plane[((mt*KB + kb)*8 + sub)*512 + ((kq)*16 + lr)*8 + kr], where node ->
// mt=node>>7, sub=(node>>4)&7, lr=node&15; k -> kb=k>>5, kq=(k>>3)&3, kr=k&7.
template <int F, int KB>
__global__ __launch_bounds__(256) void spmm_kernel(
    const float* __restrict__ x, const int* __restrict__ rp, const int* __restrict__ col,
    const float* __restrict__ inv_out, const float* __restrict__ inv_in,
    short* __restrict__ hi, short* __restrict__ lo) {
  constexpr int F4 = F / 4;
  constexpr int P4 = KB * 8;   // padded K/4
  constexpr int NI = (P4 + 63) / 64;
  int gw = (blockIdx.x * blockDim.x + threadIdx.x) >> 6;
  int lane = threadIdx.x & 63;
  int nw = (gridDim.x * blockDim.x) >> 6;
  const float4* __restrict__ x4 = (const float4*)x;
  for (int node = gw; node < NN; node += nw) {
    float4 acc[NI];
    #pragma unroll
    for (int i = 0; i < NI; ++i) acc[i] = make_float4(0.f, 0.f, 0.f, 0.f);
    int beg = rp[node], end = rp[node + 1];
    for (int j = beg; j < end; ++j) {
      int s = col[j];
      float w = inv_out[s];
      #pragma unroll
      for (int i = 0; i < NI; ++i) {
        int idx = i * 64 + lane;
        if (idx < F4) {
          float4 v = x4[(size_t)s * F4 + idx];
          acc[i].x += v.x * w;
          acc[i].y += v.y * w;
          acc[i].z += v.z * w;
          acc[i].w += v.w * w;
        }
      }
    }
    float wi = inv_in[node];
    int mt = node >> 7, sub = (node >> 4) & 7, lr = node & 15;
    size_t nbase = (((size_t)mt * KB) * 8 + sub) * 512;
    #pragma unroll
    for (int i = 0; i < NI; ++i) {
      int idx = i * 64 + lane;
      if (idx < P4) {
        float4 v = acc[i];
        v.x *= wi; v.y *= wi; v.z *= wi; v.w *= wi;
        unsigned short hx = f2bf(v.x), hy = f2bf(v.y), hz = f2bf(v.z), hw = f2bf(v.w);
        short4 h = make_short4((short)hx, (short)hy, (short)hz, (short)hw);
        short4 l = make_short4((short)f2bf(v.x - bf2f(hx)), (short)f2bf(v.y - bf2f(hy)),
                               (short)f2bf(v.z - bf2f(hz)), (short)f2bf(v.w - bf2f(hw)));
        int kb = idx >> 3, q = idx & 7;  // k = idx*4 -> kq = q>>1, kr = (q&1)*4
        size_t o = nbase + (size_t)kb * 4096 + ((q >> 1) * 16 + lr) * 8 + (q & 1) * 4;
        *(short4*)&hi[o] = h;
        *(short4*)&lo[o] = l;
      }
    }
  }
}

// ---------------------------------------------------------------- W pre-split
// W [K][Nc] fp32 -> Wh/Wl bf16, 128-col chunks in subtile-fragment order:
// chunk c = nb*KB + kb; within chunk: (rn>>4)*512 + ((kk>>3)*16 + (rn&15))*8 + (kk&7)
__global__ void wsplit(const float* __restrict__ W, short* __restrict__ Wh,
                       short* __restrict__ Wl, int K, int Nc, int KB, int NB) {
  int total = NB * KB * 4096;
  int i = blockIdx.x * blockDim.x + threadIdx.x;
  int st = gridDim.x * blockDim.x;
  for (; i < total; i += st) {
    int chunk = i >> 12;
    int e = i & 4095;
    int kk = e >> 7;           // 0..31
    int rn = e & 127;          // 0..127 (fast -> coalesced W read)
    int nb = chunk / KB;
    int kb = chunk - nb * KB;
    int n = nb * 128 + rn;
    int k = kb * 32 + kk;
    float v = (n < Nc && k < K) ? W[(size_t)k * Nc + n] : 0.f;
    unsigned short h = f2bf(v);
    unsigned short l = f2bf(v - bf2f(h));
    size_t o = (size_t)chunk * 4096 + (rn >> 4) * 512 + ((kk >> 3) * 16 + (rn & 15)) * 8 + (kk & 7);
    Wh[o] = (short)h;
    Wl[o] = (short)l;
  }
}

// ---------------------------------------------------------------- MFMA GEMM
// Dual-chain, 2-phase pipelined (global_load_lds dbuf), tile 128x128, 4 waves.
// EPI 0: out = leaky(acc1+b1) + leaky(acc2+b2)    (hop-1, two accumulators)
// EPI 1: out = acc1 + b1 + b2                     (hop-2, shared accumulator)
#define COMPUTE_STEP(BB, ACC)                                                    \
  {                                                                              \
    bf16x8 fah[4], fal[4];                                                       \
    _Pragma("unroll")                                                            \
    for (int i = 0; i < 4; ++i) {                                                \
      fah[i] = *(const bf16x8*)&lds[BB][0][(wr4 + i) * 512 + lane * 8];          \
      fal[i] = *(const bf16x8*)&lds[BB][1][(wr4 + i) * 512 + lane * 8];          \
    }                                                                            \
    _Pragma("unroll")                                                            \
    for (int j = 0; j < 4; ++j) {                                                \
      bf16x8 fbh = *(const bf16x8*)&lds[BB][2][(wc4 + j) * 512 + lane * 8];      \
      bf16x8 fbl = *(const bf16x8*)&lds[BB][3][(wc4 + j) * 512 + lane * 8];      \
      _Pragma("unroll")                                                          \
      for (int i = 0; i < 4; ++i) {                                              \
        ACC[i][j] = __builtin_amdgcn_mfma_f32_16x16x32_bf16(fah[i], fbh, ACC[i][j], 0, 0, 0); \
        ACC[i][j] = __builtin_amdgcn_mfma_f32_16x16x32_bf16(fah[i], fbl, ACC[i][j], 0, 0, 0); \
        ACC[i][j] = __builtin_amdgcn_mfma_f32_16x16x32_bf16(fal[i], fbh, ACC[i][j], 0, 0, 0); \
      }                                                                          \
    }                                                                            \
  }

#define STAGE_STEP(SS, BB)                                                       \
  {                                                                              \
    int ch_ = (SS) & 1;                                                          \
    int kb_ = (SS) >> 1;                                                         \
    const short* ah_ = ch_ ? A2h : A1h;                                          \
    const short* al_ = ch_ ? A2l : A1l;                                          \
    const short* wh_ = ch_ ? W2h : W1h;                                          \
    const short* wl_ = ch_ ? W2l : W1l;                                          \
    size_t abase_ = ((size_t)mt * KB + kb_) * 4096;                              \
    size_t wbase_ = ((size_t)nb * KB + kb_) * 4096;                              \
    _Pragma("unroll")                                                            \
    for (int c = 0; c < 2; ++c) {                                                \
      int s_ = wid * 2 + c;                                                      \
      size_t go_ = (size_t)s_ * 512 + lane * 8;                                  \
      gload16(ah_ + abase_ + go_, &lds[BB][0][s_ * 512]);                        \
      gload16(al_ + abase_ + go_, &lds[BB][1][s_ * 512]);                        \
      gload16(wh_ + wbase_ + go_, &lds[BB][2][s_ * 512]);                        \
      gload16(wl_ + wbase_ + go_, &lds[BB][3][s_ * 512]);                        \
    }                                                                            \
  }

template <int EPI>
__global__ __launch_bounds__(256, 2) void mgemm(
    const short* __restrict__ A1h, const short* __restrict__ A1l,
    const short* __restrict__ A2h, const short* __restrict__ A2l,
    const short* __restrict__ W1h, const short* __restrict__ W1l,
    const short* __restrict__ W2h, const short* __restrict__ W2l,
    const float* __restrict__ b1, const float* __restrict__ b2,
    float* __restrict__ out, int M, int Nc, int KB, int NB) {
  __shared__ short lds[2][4][4096];  // [buf][Ah,Al,Bh,Bl][128x32 frag-order]

  const int tid = threadIdx.x;
  const int nwg = gridDim.x;
  // bijective chunked XCD swizzle (m204)
  const int q = nwg >> 3, r = nwg & 7;
  const int xcd = blockIdx.x & 7, loc = blockIdx.x >> 3;
  const int wgid = ((xcd < r) ? xcd * (q + 1) : r * (q + 1) + (xcd - r) * q) + loc;
  const int nb = wgid & (NB - 1);    // NB=4 col-blocks share one A panel
  const int mt = wgid >> 2;
  const int m0 = mt * 128;
  const int n0 = nb * 128;

  const int lane = tid & 63;
  const int wid = tid >> 6;
  const int wr4 = (wid >> 1) * 4;   // wave row subtile base (0 / 4)
  const int wc4 = (wid & 1) * 4;    // wave col subtile base (0 / 4)

  f32x4 acc1[4][4], acc2[4][4];
  #pragma unroll
  for (int i = 0; i < 4; ++i)
    #pragma unroll
    for (int j = 0; j < 4; ++j) { acc1[i][j] = (f32x4)(0.f); acc2[i][j] = (f32x4)(0.f); }

  const int S = 2 * KB;
  STAGE_STEP(0, 0);
  __syncthreads();
  for (int step = 0; step < S; ++step) {
    int b = step & 1;
    if (step + 1 < S) STAGE_STEP(step + 1, b ^ 1);
    if (EPI == 0 && (step & 1)) {
      COMPUTE_STEP(b, acc2);
    } else {
      COMPUTE_STEP(b, acc1);
    }
    __syncthreads();  // drains vmcnt (next-buf DMA) + protects cur-buf reuse
  }

  // epilogue: C/D layout col = lane&15, row = (lane>>4)*4 + reg
  #pragma unroll
  for (int i = 0; i < 4; ++i) {
    #pragma unroll
    for (int rr = 0; rr < 4; ++rr) {
      int rg = m0 + wr4 * 16 + i * 16 + (lane >> 4) * 4 + rr;
      if (rg >= M) continue;
      #pragma unroll
      for (int j = 0; j < 4; ++j) {
        int c = n0 + wc4 * 16 + j * 16 + (lane & 15);
        if (c >= Nc) continue;
        float v;
        if (EPI == 0) {
          float v1 = acc1[i][j][rr] + b1[c];
          float v2 = acc2[i][j][rr] + b2[c];
          v1 = v1 > 0.f ? v1 : LEAKY * v1;
          v2 = v2 > 0.f ? v2 : LEAKY * v2;
          v = v1 + v2;
        } else {
          v = acc1[i][j][rr] + b1[c] + b2[c];
        }
        out[(size_t)rg * Nc + c] = v;
      }
    }
  }
}

// ---------------------------------------------------------------- launch
extern "C" void kernel_launch(void* const* d_in, const int* in_sizes, int n_in,
                              void* d_out, int out_size, void* d_ws, size_t ws_size,
                              hipStream_t stream) {
  const float* emb = (const float*)d_in[0];
  const float* Wa1 = (const float*)d_in[1];
  const float* ba1 = (const float*)d_in[2];
  const float* Wa2 = (const float*)d_in[3];
  const float* ba2 = (const float*)d_in[4];
  const float* Wb1 = (const float*)d_in[5];
  const float* bb1 = (const float*)d_in[6];
  const float* Wb2 = (const float*)d_in[7];
  const float* bb2 = (const float*)d_in[8];
  const int* src1 = (const int*)d_in[9];
  const int* dst1 = (const int*)d_in[10];
  const int* src2 = (const int*)d_in[11];
  const int* dst2 = (const int*)d_in[12];
  float* out = (float*)d_out;

  char* ws = (char*)d_ws;
  size_t off = 0;
  auto alloc = [&](size_t nbytes) -> void* {
    off = (off + 255) & ~(size_t)255;
    void* p = ws + off;
    off += nbytes;
    return p;
  };
  int* od1 = (int*)alloc(NN * 4);
  int* id1 = (int*)alloc(NN * 4);
  int* od2 = (int*)alloc(NN * 4);
  int* id2 = (int*)alloc(NN * 4);
  int* fill1 = (int*)alloc(NN * 4);
  int* fill2 = (int*)alloc(NN * 4);
  int* rp1 = (int*)alloc((NN + 1) * 4);
  int* rp2 = (int*)alloc((NN + 1) * 4);
  int* col1 = (int*)alloc((size_t)NE * 4);
  int* col2 = (int*)alloc((size_t)NE * 4);
  float* io1 = (float*)alloc(NN * 4);
  float* ii1 = (float*)alloc(NN * 4);
  float* io2 = (float*)alloc(NN * 4);
  float* ii2 = (float*)alloc(NN * 4);
  const int KB1 = 10;   // K=300 -> 10 k-tiles (pad 320)
  const int KB2 = 13;   // K=400 -> 13 k-tiles (pad 416)
  const int NB1 = 4;    // Nc=400 -> 4 col-blocks of 128
  const int NB2 = 4;    // Nc=512 -> 4 col-blocks
  const int NM = (NN + 127) / 128;  // 391 row tiles
  short* Wa1h = (short*)alloc((size_t)NB1 * KB1 * 4096 * 2);
  short* Wa1l = (short*)alloc((size_t)NB1 * KB1 * 4096 * 2);
  short* Wb1h = (short*)alloc((size_t)NB1 * KB1 * 4096 * 2);
  short* Wb1l = (short*)alloc((size_t)NB1 * KB1 * 4096 * 2);
  short* Wa2h = (short*)alloc((size_t)NB2 * KB2 * 4096 * 2);
  short* Wa2l = (short*)alloc((size_t)NB2 * KB2 * 4096 * 2);
  short* Wb2h = (short*)alloc((size_t)NB2 * KB2 * 4096 * 2);
  short* Wb2l = (short*)alloc((size_t)NB2 * KB2 * 4096 * 2);
  // A planes in tiled-fragment order, sized for KB2 (covers KB1 too)
  size_t aplane = (size_t)NM * KB2 * 4096;
  short* A1h = (short*)alloc(aplane * 2);
  short* A1l = (short*)alloc(aplane * 2);
  short* A2h = (short*)alloc(aplane * 2);
  short* A2l = (short*)alloc(aplane * 2);
  float* X = (float*)d_out;  // hop-1 intermediate [NN x 400] lives in d_out

  int nz = (int)(((char*)fill2 - (char*)od1) / 4) + NN;
  zero_ints<<<256, 256, 0, stream>>>(od1, nz);

  deg_kernel<<<1024, 256, 0, stream>>>(src1, dst1, src2, dst2, od1, id1, od2, id2);
  scale_kernel<<<(NN + 255) / 256, 256, 0, stream>>>(od1, id1, od2, id2, io1, ii1, io2, ii2);
  scan_kernel<<<2, 1024, 0, stream>>>(id1, id2, rp1, rp2);
  fill_kernel<<<1024, 256, 0, stream>>>(src1, dst1, src2, dst2, rp1, rp2,
                                        fill1, fill2, col1, col2);

  wsplit<<<640, 256, 0, stream>>>(Wa1, Wa1h, Wa1l, 300, 400, KB1, NB1);
  wsplit<<<640, 256, 0, stream>>>(Wb1, Wb1h, Wb1l, 300, 400, KB1, NB1);
  wsplit<<<832, 256, 0, stream>>>(Wa2, Wa2h, Wa2l, 400, 512, KB2, NB2);
  wsplit<<<832, 256, 0, stream>>>(Wb2, Wb2h, Wb2l, 400, 512, KB2, NB2);

  // hop 1: X = leaky(agg1@Wa1+ba1) + leaky(agg2@Wb1+bb1)   (one fused GEMM)
  spmm_kernel<300, KB1><<<12500, 256, 0, stream>>>(emb, rp1, col1, io1, ii1, A1h, A1l);
  spmm_kernel<300, KB1><<<12500, 256, 0, stream>>>(emb, rp2, col2, io2, ii2, A2h, A2l);
  mgemm<0><<<NB1 * NM, 256, 0, stream>>>(A1h, A1l, A2h, A2l, Wa1h, Wa1l, Wb1h, Wb1l,
                                         ba1, bb1, X, NN, 400, KB1, NB1);

  // hop 2: out = agg1@Wa2 + agg2@Wb2 + ba2 + bb2           (one fused GEMM)
  spmm_kernel<400, KB2><<<12500, 256, 0, stream>>>(X, rp1, col1, io1, ii1, A1h, A1l);
  spmm_kernel<400, KB2><<<12500, 256, 0, stream>>>(X, rp2, col2, io2, ii2, A2h, A2l);
  mgemm<1><<<NB2 * NM, 256, 0, stream>>>(A1h, A1l, A2h, A2l, Wa2h, Wa2l, Wb2h, Wb2l,
                                         ba2, bb2, out, NN, 512, KB2, NB2);
}